// Round 1
// baseline (741.776 us; speedup 1.0000x reference)
//
#include <hip/hip_runtime.h>

// CrossEntropyLoss_37254546326109 — fused CE + VAR + Inter + Center loss.
// logit [8,21,512,512] f32, target [8,1,512,512] i32, features [8,262144,32] f32.
// loss = (CE + 1.0*VAR + 0.5*Inter + 0.1*Center)/8, scalar f32 output.

constexpr int   N_IMG  = 8;
constexpr int   C_CLS  = 21;
constexpr int   P_PIX  = 512 * 512;     // 262144 pixels per image
constexpr int   PQ     = P_PIX / 4;     // 65536 float4-quads per image per channel
constexpr int   IGN    = 255;
constexpr float ALPHA  = 1.0f, BETA = 0.5f, GAMMA = 0.1f;

// Workspace layout (floats):
//  [0] ce_sum  [1] vm_sum  [2] var_sum (= sum -lg*vm)  [3] inter_sum  [4] ssq_sum
//  [16 .. 16+8*21*32)   per-(img,class) feature sums S
//  [5392 .. 5392+168)   per-(img,class) valid counts
constexpr int WS_SUMS   = 16;
constexpr int WS_CNT    = WS_SUMS + N_IMG * C_CLS * 32;   // 5392
constexpr int WS_FLOATS = WS_CNT + N_IMG * C_CLS;         // 5560

// ---------------------------------------------------------------------------
// Kernel 1: per-pixel logit terms. One thread = 4 pixels (float4 across the
// pixel dim; channel stride is P so every channel load is fully coalesced).
// No max-subtraction in logsumexp: logits are ~N(0,1), exp() is safe in f32.
// ---------------------------------------------------------------------------
__global__ __launch_bounds__(256) void pixel_kernel(
    const float* __restrict__ logit, const int* __restrict__ target,
    float* __restrict__ ws)
{
    const int q   = blockIdx.x * 256 + threadIdx.x;   // global quad id
    const int img = q >> 16;                          // q / PQ
    const int pq  = q & (PQ - 1);

    const int4 t = ((const int4*)target)[(size_t)img * PQ + pq];
    const float4* lp = (const float4*)logit + (size_t)img * C_CLS * PQ + pq;

    float4 s  = {0.f, 0.f, 0.f, 0.f};   // sum exp
    float4 sc = {0.f, 0.f, 0.f, 0.f};   // sum logits
    float4 lg = {0.f, 0.f, 0.f, 0.f};   // logit at own label
#pragma unroll
    for (int ch = 0; ch < C_CLS; ++ch) {
        const float4 x = lp[(size_t)ch * PQ];
        s.x += __expf(x.x); s.y += __expf(x.y); s.z += __expf(x.z); s.w += __expf(x.w);
        sc.x += x.x; sc.y += x.y; sc.z += x.z; sc.w += x.w;
        lg.x = (t.x == ch) ? x.x : lg.x;
        lg.y = (t.y == ch) ? x.y : lg.y;
        lg.z = (t.z == ch) ? x.z : lg.z;
        lg.w = (t.w == ch) ? x.w : lg.w;
    }

    float ce = 0.f, vm = 0.f, var = 0.f, inter = 0.f;
    {
        const float v = (t.x != IGN) ? 1.f : 0.f;
        vm += v; ce += v * (__logf(s.x) - lg.x); var -= v * lg.x; inter += v * (sc.x - lg.x);
    }
    {
        const float v = (t.y != IGN) ? 1.f : 0.f;
        vm += v; ce += v * (__logf(s.y) - lg.y); var -= v * lg.y; inter += v * (sc.y - lg.y);
    }
    {
        const float v = (t.z != IGN) ? 1.f : 0.f;
        vm += v; ce += v * (__logf(s.z) - lg.z); var -= v * lg.z; inter += v * (sc.z - lg.z);
    }
    {
        const float v = (t.w != IGN) ? 1.f : 0.f;
        vm += v; ce += v * (__logf(s.w) - lg.w); var -= v * lg.w; inter += v * (sc.w - lg.w);
    }

    // wave64 butterfly reduce, then one set of atomics per block
    for (int off = 32; off; off >>= 1) {
        ce    += __shfl_xor(ce, off);
        vm    += __shfl_xor(vm, off);
        var   += __shfl_xor(var, off);
        inter += __shfl_xor(inter, off);
    }
    __shared__ float red[4][4];
    const int wv = threadIdx.x >> 6;
    if ((threadIdx.x & 63) == 0) {
        red[wv][0] = ce; red[wv][1] = vm; red[wv][2] = var; red[wv][3] = inter;
    }
    __syncthreads();
    if (threadIdx.x < 4) {
        const float v = red[0][threadIdx.x] + red[1][threadIdx.x]
                      + red[2][threadIdx.x] + red[3][threadIdx.x];
        atomicAdd(&ws[threadIdx.x], v);
    }
}

// ---------------------------------------------------------------------------
// Kernel 2: Center-loss statistics. Block = 1024 pixels of one image.
// Thread tid reads float4 at float-offset 4*tid within a 32-pixel slab
// (perfectly coalesced). LDS class sums padded to stride 33 so the LDS-atomic
// bank is (lab + 4*dq + k) % 32 — random labels spread banks (~2-way, free).
// ---------------------------------------------------------------------------
__global__ __launch_bounds__(256) void feature_kernel(
    const float* __restrict__ feats, const int* __restrict__ target,
    float* __restrict__ ws)
{
    __shared__ float s_sums[C_CLS * 33];   // padded stride
    __shared__ float s_cnt[C_CLS];
    __shared__ float s_red[4];

    const int tid   = threadIdx.x;
    const int img   = blockIdx.x >> 8;       // 256 blocks per image
    const int chunk = blockIdx.x & 255;
    const int p0    = chunk * 1024;

    for (int i = tid; i < C_CLS * 33; i += 256) s_sums[i] = 0.f;
    if (tid < C_CLS) s_cnt[tid] = 0.f;
    __syncthreads();

    const float4* fb = (const float4*)feats + (size_t)img * P_PIX * 8;
    const int*    tb = target + (size_t)img * P_PIX + p0;
    const int dq4 = (tid & 7) * 4;   // first dim this thread covers
    const int pl  = tid >> 3;        // pixel lane within 32-pixel slab

    float ssq = 0.f;
    for (int it = 0; it < 32; ++it) {
        const int lab = tb[it * 32 + pl];
        const float4 f = fb[(size_t)(p0 + it * 32) * 8 + tid];
        if (lab != IGN) {
            ssq += f.x * f.x + f.y * f.y + f.z * f.z + f.w * f.w;
            float* dst = &s_sums[lab * 33 + dq4];
            atomicAdd(dst + 0, f.x);
            atomicAdd(dst + 1, f.y);
            atomicAdd(dst + 2, f.z);
            atomicAdd(dst + 3, f.w);
            if ((tid & 7) == 0) atomicAdd(&s_cnt[lab], 1.f);
        }
    }

    // block-reduce ssq -> one global atomic
    for (int off = 32; off; off >>= 1) ssq += __shfl_xor(ssq, off);
    if ((tid & 63) == 0) s_red[tid >> 6] = ssq;
    __syncthreads();   // also orders the LDS atomics before the flush reads
    if (tid == 0) atomicAdd(&ws[4], s_red[0] + s_red[1] + s_red[2] + s_red[3]);

    // flush class sums / counts to global accumulators
    for (int i = tid; i < C_CLS * 32; i += 256) {
        const int c = i >> 5, d = i & 31;
        const float v = s_sums[c * 33 + d];
        if (v != 0.f) atomicAdd(&ws[WS_SUMS + img * C_CLS * 32 + i], v);
    }
    if (tid < C_CLS) {
        const float c = s_cnt[tid];
        if (c != 0.f) atomicAdd(&ws[WS_CNT + img * C_CLS + tid], c);
    }
}

// ---------------------------------------------------------------------------
// Kernel 3: combine. 168 (img,class) mean-terms + the 5 scalars.
// ---------------------------------------------------------------------------
__global__ __launch_bounds__(256) void finalize_kernel(
    const float* __restrict__ ws, float* __restrict__ out)
{
    float part = 0.f;
    const int i = threadIdx.x;
    if (i < N_IMG * C_CLS) {
        const float* S = ws + WS_SUMS + i * 32;
        float n2 = 0.f;
#pragma unroll
        for (int d = 0; d < 32; ++d) n2 += S[d] * S[d];
        part = n2 / fmaxf(ws[WS_CNT + i], 1.f);
    }
    for (int off = 32; off; off >>= 1) part += __shfl_xor(part, off);
    __shared__ float red[4];
    if ((threadIdx.x & 63) == 0) red[threadIdx.x >> 6] = part;
    __syncthreads();
    if (threadIdx.x == 0) {
        const float meansum = red[0] + red[1] + red[2] + red[3];
        const float invP   = 1.f / (float)P_PIX;
        const float CE     = ws[0] / fmaxf(ws[1], 1.f);
        const float VAR    = ws[2] * invP;
        const float Inter  = ws[3] * invP;
        const float Center = (ws[4] - meansum) * invP;
        out[0] = (CE + ALPHA * VAR + BETA * Inter + GAMMA * Center) / (float)N_IMG;
    }
}

extern "C" void kernel_launch(void* const* d_in, const int* in_sizes, int n_in,
                              void* d_out, int out_size, void* d_ws, size_t ws_size,
                              hipStream_t stream)
{
    const float* logit  = (const float*)d_in[0];
    const int*   target = (const int*)d_in[1];
    const float* feats  = (const float*)d_in[2];
    float* ws  = (float*)d_ws;
    float* out = (float*)d_out;

    // zero accumulators (ws is poisoned 0xAA before every call)
    hipMemsetAsync(d_ws, 0, WS_FLOATS * sizeof(float), stream);

    pixel_kernel<<<N_IMG * PQ / 256, 256, 0, stream>>>(logit, target, ws);
    feature_kernel<<<N_IMG * (P_PIX / 1024), 256, 0, stream>>>(feats, target, ws);
    finalize_kernel<<<1, 256, 0, stream>>>(ws, out);
}

// Round 2
// 505.746 us; speedup vs baseline: 1.4667x; 1.4667x over previous
//
#include <hip/hip_runtime.h>

// CrossEntropyLoss_37254546326109 — fused CE + VAR + Inter + Center loss.
// logit [8,21,512,512] f32, target [8,1,512,512] i32, features [8,262144,32] f32.
// loss = (CE + 1.0*VAR + 0.5*Inter + 0.1*Center)/8, scalar f32 output.
//
// R1 lesson: fp32 atomicAdd (global AND shared) compiles to CAS retry loops
// without -munsafe-fp-atomics; contended CAS dominated both kernels (~352 us
// each, VALUBusy 2%, HBM 5%). This version has ZERO fp32 atomics: per-block
// partials + tree reductions. Only int LDS atomics (native ds_add_u32) remain.

constexpr int   N_IMG  = 8;
constexpr int   C_CLS  = 21;
constexpr int   P_PIX  = 512 * 512;     // pixels per image
constexpr int   PQ     = P_PIX / 4;     // float4-quads per image per channel
constexpr int   IGN    = 255;
constexpr float ALPHA  = 1.0f, BETA = 0.5f, GAMMA = 0.1f;

constexpr int PIX_BLOCKS  = 2048;   // 256 per image, 256 quads (1024 px) each
constexpr int FEAT_BLOCKS = 1024;   // 128 per image, 2048 px each
constexpr int FEAT_ITERS  = 64;     // 32 px per iteration per block

// Workspace layout (4-byte units). Total ~2.9 MB.
constexpr int OFF_PIX  = 0;                              // [2048][4] f32
constexpr int OFF_SSQ  = OFF_PIX + PIX_BLOCKS * 4;       // [1024]    f32
constexpr int OFF_CLS  = OFF_SSQ + FEAT_BLOCKS;          // [1024][672] f32
constexpr int OFF_CNT  = OFF_CLS + FEAT_BLOCKS * 672;    // [2048][21] i32
constexpr int OFF_MEAN = OFF_CNT + PIX_BLOCKS * C_CLS;   // [168] f32

// ---------------------------------------------------------------------------
// Kernel 1: per-pixel logit terms + label histogram. One thread = 4 pixels
// (float4 across pixels; channel stride PQ -> fully coalesced). All 21
// channel loads issued up front (x[21] in registers) so vmcnt pipelines.
// Logits ~N(0,1): logsumexp without max-subtraction is safe in f32.
// ---------------------------------------------------------------------------
__global__ __launch_bounds__(256, 4) void pixel_kernel(
    const float* __restrict__ logit, const int* __restrict__ target,
    float* __restrict__ ws)
{
    __shared__ int   s_hist[C_CLS];
    __shared__ float s_red[4][4];

    const int tid = threadIdx.x;
    if (tid < C_CLS) s_hist[tid] = 0;
    __syncthreads();

    const int q   = blockIdx.x * 256 + tid;
    const int img = q >> 16;
    const int pq  = q & (PQ - 1);

    const int4 t = ((const int4*)target)[(size_t)img * PQ + pq];
    const float4* lp = (const float4*)logit + (size_t)img * C_CLS * PQ + pq;

    float4 x[C_CLS];
#pragma unroll
    for (int ch = 0; ch < C_CLS; ++ch) x[ch] = lp[(size_t)ch * PQ];

    float4 s  = {0.f, 0.f, 0.f, 0.f};
    float4 sc = {0.f, 0.f, 0.f, 0.f};
    float4 lg = {0.f, 0.f, 0.f, 0.f};
#pragma unroll
    for (int ch = 0; ch < C_CLS; ++ch) {
        const float4 v = x[ch];
        s.x += __expf(v.x); s.y += __expf(v.y); s.z += __expf(v.z); s.w += __expf(v.w);
        sc.x += v.x; sc.y += v.y; sc.z += v.z; sc.w += v.w;
        lg.x = (t.x == ch) ? v.x : lg.x;
        lg.y = (t.y == ch) ? v.y : lg.y;
        lg.z = (t.z == ch) ? v.z : lg.z;
        lg.w = (t.w == ch) ? v.w : lg.w;
    }

    // label histogram (int LDS atomics are native ds_add_u32)
    if (t.x != IGN) atomicAdd(&s_hist[t.x], 1);
    if (t.y != IGN) atomicAdd(&s_hist[t.y], 1);
    if (t.z != IGN) atomicAdd(&s_hist[t.z], 1);
    if (t.w != IGN) atomicAdd(&s_hist[t.w], 1);

    float ce = 0.f, vm = 0.f, var = 0.f, inter = 0.f;
    {
        const float v = (t.x != IGN) ? 1.f : 0.f;
        vm += v; ce += v * (__logf(s.x) - lg.x); var -= v * lg.x; inter += v * (sc.x - lg.x);
    }
    {
        const float v = (t.y != IGN) ? 1.f : 0.f;
        vm += v; ce += v * (__logf(s.y) - lg.y); var -= v * lg.y; inter += v * (sc.y - lg.y);
    }
    {
        const float v = (t.z != IGN) ? 1.f : 0.f;
        vm += v; ce += v * (__logf(s.z) - lg.z); var -= v * lg.z; inter += v * (sc.z - lg.z);
    }
    {
        const float v = (t.w != IGN) ? 1.f : 0.f;
        vm += v; ce += v * (__logf(s.w) - lg.w); var -= v * lg.w; inter += v * (sc.w - lg.w);
    }

    for (int off = 32; off; off >>= 1) {
        ce    += __shfl_xor(ce, off);
        vm    += __shfl_xor(vm, off);
        var   += __shfl_xor(var, off);
        inter += __shfl_xor(inter, off);
    }
    const int wv = tid >> 6;
    if ((tid & 63) == 0) {
        s_red[wv][0] = ce; s_red[wv][1] = vm; s_red[wv][2] = var; s_red[wv][3] = inter;
    }
    __syncthreads();   // also orders the histogram atomics

    if (tid < 4) {
        ws[OFF_PIX + blockIdx.x * 4 + tid] =
            s_red[0][tid] + s_red[1][tid] + s_red[2][tid] + s_red[3][tid];
    }
    if (tid < C_CLS) {
        ((int*)ws)[OFF_CNT + blockIdx.x * C_CLS + tid] = s_hist[tid];
    }
}

// ---------------------------------------------------------------------------
// Kernel 2: Center-loss class sums via REGISTER accumulators (no atomics).
// 256 threads = 32 pixel-lanes x 8 dim-groups. Thread holds float4 acc[21];
// per pixel: masked FMA per class (VALU was idle — spend it). Loads are
// software-pipelined one iteration ahead. Block reduce: wave shuffle over
// pixel-lane bits, then LDS across waves, write 672-float partial per block.
// ---------------------------------------------------------------------------
__global__ __launch_bounds__(256, 4) void feature_kernel(
    const float* __restrict__ feats, const int* __restrict__ target,
    float* __restrict__ ws)
{
    __shared__ float4 s_part[4][8][C_CLS];   // [wave][dimgroup][class]
    __shared__ float  s_red[4];

    const int tid   = threadIdx.x;
    const int img   = blockIdx.x >> 7;       // 128 blocks per image
    const int chunk = blockIdx.x & 127;
    const int p0    = chunk * 2048;
    const int pl    = tid >> 3;              // pixel lane 0..31
    const int dg    = tid & 7;               // dim group 0..7

    const float4* fb = (const float4*)feats + ((size_t)img * P_PIX + p0) * 8;
    const int*    tb = target + (size_t)img * P_PIX + p0;

    float4 acc[C_CLS];
#pragma unroll
    for (int c = 0; c < C_CLS; ++c) acc[c] = {0.f, 0.f, 0.f, 0.f};
    float ssq = 0.f;

    int    lab = tb[pl];
    float4 f   = fb[(size_t)pl * 8 + dg];
    for (int it = 0; it < FEAT_ITERS; ++it) {
        int    nlab = 0;
        float4 nf   = {0.f, 0.f, 0.f, 0.f};
        if (it + 1 < FEAT_ITERS) {
            nlab = tb[(it + 1) * 32 + pl];
            nf   = fb[(size_t)((it + 1) * 32 + pl) * 8 + dg];
        }
        const float vld = (lab != IGN) ? 1.f : 0.f;
        ssq += vld * (f.x * f.x + f.y * f.y + f.z * f.z + f.w * f.w);
#pragma unroll
        for (int c = 0; c < C_CLS; ++c) {
            const float m = (lab == c) ? 1.f : 0.f;
            acc[c].x += m * f.x; acc[c].y += m * f.y;
            acc[c].z += m * f.z; acc[c].w += m * f.w;
        }
        lab = nlab; f = nf;
    }

    // reduce across the 8 pixel-lanes sharing this dim-group within the wave
#pragma unroll
    for (int c = 0; c < C_CLS; ++c) {
        for (int off = 8; off <= 32; off <<= 1) {
            acc[c].x += __shfl_xor(acc[c].x, off);
            acc[c].y += __shfl_xor(acc[c].y, off);
            acc[c].z += __shfl_xor(acc[c].z, off);
            acc[c].w += __shfl_xor(acc[c].w, off);
        }
    }
    const int wv = tid >> 6;
    if ((tid & 63) < 8) {
#pragma unroll
        for (int c = 0; c < C_CLS; ++c) s_part[wv][dg][c] = acc[c];
    }

    for (int off = 1; off < 64; off <<= 1) ssq += __shfl_xor(ssq, off);
    if ((tid & 63) == 0) s_red[wv] = ssq;
    __syncthreads();

    if (tid < C_CLS * 8) {             // 168 threads: one float4 each
        const int c = tid >> 3, g = tid & 7;
        const float4 a = s_part[0][g][c], b = s_part[1][g][c];
        const float4 d = s_part[2][g][c], e = s_part[3][g][c];
        float4 v;
        v.x = a.x + b.x + d.x + e.x;
        v.y = a.y + b.y + d.y + e.y;
        v.z = a.z + b.z + d.z + e.z;
        v.w = a.w + b.w + d.w + e.w;
        // float offset: blk*672 + c*32 + g*4  (matches reduce_kernel)
        ((float4*)(ws + OFF_CLS))[(size_t)blockIdx.x * 168 + tid] = v;
    }
    if (tid == 0)
        ws[OFF_SSQ + blockIdx.x] = s_red[0] + s_red[1] + s_red[2] + s_red[3];
}

// ---------------------------------------------------------------------------
// Kernel 3: fold class-sum partials + count partials into 168 mean-terms.
// One block per (img, class). 128 threads.
// ---------------------------------------------------------------------------
__global__ __launch_bounds__(128) void reduce_kernel(float* __restrict__ ws)
{
    __shared__ float sred[128];
    __shared__ int   s_cnt;

    const int img = blockIdx.x / C_CLS;
    const int c   = blockIdx.x % C_CLS;
    const int tid = threadIdx.x;
    const int d   = tid & 31;         // dim
    const int qq  = tid >> 5;         // 0..3

    if (tid == 0) s_cnt = 0;
    __syncthreads();

    // counts: sum this image's 256 pixel-block histograms
    int cnt = 0;
    const int* cp = (const int*)ws + OFF_CNT;
    for (int b = tid; b < 256; b += 128) cnt += cp[(img * 256 + b) * C_CLS + c];
    atomicAdd(&s_cnt, cnt);

    // class sums: sum this image's 128 feature-block partials for (c, d)
    float s = 0.f;
    for (int b = qq; b < 128; b += 4)
        s += ws[OFF_CLS + (size_t)(img * 128 + b) * 672 + c * 32 + d];
    sred[tid] = s;
    __syncthreads();                  // also orders s_cnt atomics
    if (tid < 64) sred[tid] += sred[tid + 64];
    __syncthreads();
    if (tid < 32) {
        const float Sd = sred[tid] + sred[tid + 32];
        float n2 = Sd * Sd;
        for (int off = 1; off < 32; off <<= 1) n2 += __shfl_xor(n2, off);
        if (tid == 0)
            ws[OFF_MEAN + blockIdx.x] = n2 / fmaxf((float)s_cnt, 1.f);
    }
}

// ---------------------------------------------------------------------------
// Kernel 4: final combine.
// ---------------------------------------------------------------------------
__global__ __launch_bounds__(256) void finalize_kernel(
    const float* __restrict__ ws, float* __restrict__ out)
{
    __shared__ float fr[4][6];
    const int tid = threadIdx.x;

    float ce = 0.f, vm = 0.f, var = 0.f, inter = 0.f, ssq = 0.f, mean = 0.f;
    for (int b = tid; b < PIX_BLOCKS; b += 256) {
        const float* p = ws + OFF_PIX + b * 4;
        ce += p[0]; vm += p[1]; var += p[2]; inter += p[3];
    }
    for (int b = tid; b < FEAT_BLOCKS; b += 256) ssq += ws[OFF_SSQ + b];
    if (tid < N_IMG * C_CLS) mean = ws[OFF_MEAN + tid];

    for (int off = 32; off; off >>= 1) {
        ce   += __shfl_xor(ce, off);   vm    += __shfl_xor(vm, off);
        var  += __shfl_xor(var, off);  inter += __shfl_xor(inter, off);
        ssq  += __shfl_xor(ssq, off);  mean  += __shfl_xor(mean, off);
    }
    const int wv = tid >> 6;
    if ((tid & 63) == 0) {
        fr[wv][0] = ce;  fr[wv][1] = vm;   fr[wv][2] = var;
        fr[wv][3] = inter; fr[wv][4] = ssq; fr[wv][5] = mean;
    }
    __syncthreads();
    if (tid == 0) {
        const float CE_s  = fr[0][0] + fr[1][0] + fr[2][0] + fr[3][0];
        const float VM    = fr[0][1] + fr[1][1] + fr[2][1] + fr[3][1];
        const float VAR_s = fr[0][2] + fr[1][2] + fr[2][2] + fr[3][2];
        const float INT_s = fr[0][3] + fr[1][3] + fr[2][3] + fr[3][3];
        const float SSQ   = fr[0][4] + fr[1][4] + fr[2][4] + fr[3][4];
        const float MEAN  = fr[0][5] + fr[1][5] + fr[2][5] + fr[3][5];
        const float invP   = 1.f / (float)P_PIX;
        const float CE     = CE_s / fmaxf(VM, 1.f);
        const float VAR    = VAR_s * invP;
        const float Inter  = INT_s * invP;
        const float Center = (SSQ - MEAN) * invP;
        out[0] = (CE + ALPHA * VAR + BETA * Inter + GAMMA * Center) / (float)N_IMG;
    }
}

extern "C" void kernel_launch(void* const* d_in, const int* in_sizes, int n_in,
                              void* d_out, int out_size, void* d_ws, size_t ws_size,
                              hipStream_t stream)
{
    const float* logit  = (const float*)d_in[0];
    const int*   target = (const int*)d_in[1];
    const float* feats  = (const float*)d_in[2];
    float* ws  = (float*)d_ws;
    float* out = (float*)d_out;

    // No memset needed: every ws word consumed is written earlier in-stream.
    pixel_kernel  <<<PIX_BLOCKS, 256, 0, stream>>>(logit, target, ws);
    feature_kernel<<<FEAT_BLOCKS, 256, 0, stream>>>(feats, target, ws);
    reduce_kernel <<<N_IMG * C_CLS, 128, 0, stream>>>(ws);
    finalize_kernel<<<1, 256, 0, stream>>>(ws, out);
}